// Round 5
// baseline (2893.124 us; speedup 1.0000x reference)
//
#include <hip/hip_runtime.h>

#define N_SUP 8192
#define N_QPT 2048

typedef float v2f __attribute__((ext_vector_type(2)));

// ---------------------------------------------------------------------------
// Exactness helpers: the reference index selection (FPS argmax, ball-query
// membership) must match numpy's plain fp32 arithmetic bit-for-bit, so fma
// contraction is disabled for these expressions.
// ---------------------------------------------------------------------------
__device__ __forceinline__ float sumsq3(float x, float y, float z) {
#pragma clang fp contract(off)
  return x * x + y * y + z * z;  // ((x*x + y*y) + z*z)
}

__device__ __forceinline__ float dot3(float ax, float ay, float az,
                                      float bx, float by, float bz) {
#pragma clang fp contract(off)
  return ax * bx + ay * by + az * bz;
}

__device__ __forceinline__ float d2_expand(float A, float Bn, float d) {
#pragma clang fp contract(off)
  return (A + Bn) - 2.0f * d;  // matches (|q|^2 + |s|^2) - 2*dot
}

// u64 wave-max via DPP halves (row_shr 1/2/4/8, row_bcast15/31); lane 63 ends
// with the wave max. old=src => invalid lanes keep own value (identity).
template <int CTRL>
__device__ __forceinline__ unsigned long long dppmax64(unsigned long long k) {
  unsigned lo = (unsigned)k, hi = (unsigned)(k >> 32);
  unsigned olo =
      (unsigned)__builtin_amdgcn_update_dpp((int)lo, (int)lo, CTRL, 0xf, 0xf, false);
  unsigned ohi =
      (unsigned)__builtin_amdgcn_update_dpp((int)hi, (int)hi, CTRL, 0xf, 0xf, false);
  unsigned long long o = (((unsigned long long)ohi) << 32) | olo;
  return (o > k) ? o : k;
}

__device__ __forceinline__ unsigned long long wavemax_u64(unsigned long long k) {
  k = dppmax64<0x111>(k);  // row_shr:1
  k = dppmax64<0x112>(k);  // row_shr:2
  k = dppmax64<0x114>(k);  // row_shr:4
  k = dppmax64<0x118>(k);  // row_shr:8
  k = dppmax64<0x142>(k);  // row_bcast15
  k = dppmax64<0x143>(k);  // row_bcast31 -> lane 63 = wave max
  return k;
}

// ---------------------------------------------------------------------------
// prep: xyz (B,N,3) -> SoA xs/ys/zs + per-point squared norms
// ---------------------------------------------------------------------------
__global__ __launch_bounds__(256) void prep_xyz_kernel(
    const float* __restrict__ xyz, float* __restrict__ xs,
    float* __restrict__ ys, float* __restrict__ zs, float* __restrict__ bsq) {
  int p = blockIdx.x * 256 + threadIdx.x;  // 0..B*N-1
  float x = xyz[p * 3 + 0];
  float y = xyz[p * 3 + 1];
  float z = xyz[p * 3 + 2];
  xs[p] = x; ys[p] = y; zs[p] = z;
  bsq[p] = sumsq3(x, y, z);
}

// ---------------------------------------------------------------------------
// transpose features (B,C=64,N) -> (B,N,64) for coalesced gathers
// ---------------------------------------------------------------------------
__global__ __launch_bounds__(256) void transpose_feats_kernel(
    const float* __restrict__ feats, float* __restrict__ fT) {
  __shared__ float tile[64][65];
  int b = blockIdx.x >> 7;           // 128 n-tiles per batch
  int nb = (blockIdx.x & 127) << 6;
  int t = threadIdx.x;
#pragma unroll
  for (int i = 0; i < 16; ++i) {
    int e = i * 256 + t;
    int c = e >> 6, n = e & 63;     // consecutive lanes -> consecutive n
    tile[n][c] = feats[(b * 64 + c) * N_SUP + nb + n];
  }
  __syncthreads();
#pragma unroll
  for (int i = 0; i < 16; ++i) {
    int e = i * 256 + t;
    int n = e >> 6, c = e & 63;     // consecutive lanes -> consecutive c
    fT[(b * N_SUP + nb + n) * 64 + c] = tile[n][c];
  }
}

// ---------------------------------------------------------------------------
// FPS with EXACT spatial pruning (thread-granule QuickFPS).
// One block per batch, 512 threads. Setup: bin-sort points by 8^3 grid cell
// into an LDS mirror; each thread takes 16 spatially-local sorted points into
// registers + their bounding box. Per iteration:
//   - dirty check: distbox2(p_new, thread box) < tval*1.0001+1e-12 ?
//     (dm only decreases; skipping is provably exact with the fp margin --
//      over-updating is always exact, so the margin only costs extra work)
//   - dirty threads re-sweep their 16 register points (same fp32 formula as
//     brute force), rebuild their key (dm_max<<32 | invorig<<13 | sortedpos);
//     u64 max == numpy argmax with first-original-index tie-break.
//   - wave with any dirty lane re-reduces (DPP u64); lane63 caches wave key
//     and writes it to the parity slot every iteration (cheap).
//   - ONE barrier; all waves fold 8 slot keys; winner coords from LDS mirror.
// ---------------------------------------------------------------------------
__global__ __launch_bounds__(512, 1) void fps_kernel(
    const float* __restrict__ xs, const float* __restrict__ ys,
    const float* __restrict__ zs, float* __restrict__ qxyz) {
  const int b = blockIdx.x;
  const int t = threadIdx.x;
  __shared__ float sx[N_SUP], sy[N_SUP], sz[N_SUP];      // sorted coords 96 KB
  __shared__ unsigned short sorig[N_SUP];                // 16 KB
  __shared__ unsigned int hist[512], offs[512], cursor[512];  // 6 KB
  __shared__ __align__(16) unsigned long long skey[2][8];
  const float* bx = xs + b * N_SUP;
  const float* by = ys + b * N_SUP;
  const float* bz = zs + b * N_SUP;

  // ---- setup: bin-sort by 8^3 cell into LDS ----
  hist[t] = 0u;
  __syncthreads();
  for (int j = 0; j < 16; ++j) {
    int n = t + j * 512;
    float x = bx[n], y = by[n], z = bz[n];
    int cx = min(7, (int)(x * 8.0f));
    int cy = min(7, (int)(y * 8.0f));
    int cz = min(7, (int)(z * 8.0f));
    atomicAdd(&hist[(cx << 6) | (cy << 3) | cz], 1u);
  }
  __syncthreads();
  offs[t] = hist[t];
  __syncthreads();
  for (int d = 1; d < 512; d <<= 1) {  // Hillis-Steele inclusive scan
    unsigned v = (t >= d) ? offs[t - d] : 0u;
    __syncthreads();
    offs[t] += v;
    __syncthreads();
  }
  cursor[t] = offs[t] - hist[t];  // exclusive start
  __syncthreads();
  for (int j = 0; j < 16; ++j) {
    int n = t + j * 512;
    float x = bx[n], y = by[n], z = bz[n];
    int cx = min(7, (int)(x * 8.0f));
    int cy = min(7, (int)(y * 8.0f));
    int cz = min(7, (int)(z * 8.0f));
    unsigned pos = atomicAdd(&cursor[(cx << 6) | (cy << 3) | cz], 1u);
    sx[pos] = x; sy[pos] = y; sz[pos] = z;
    sorig[pos] = (unsigned short)n;
  }
  __syncthreads();

  // ---- load 16 sorted points into registers; box; payloads ----
  v2f px[8], py[8], pz[8], dm[8];
  unsigned payx[8], payy[8];
  const int base = t * 16;
#pragma unroll
  for (int j = 0; j < 8; ++j) {
    int p0 = base + 2 * j, p1 = p0 + 1;
    px[j] = (v2f){sx[p0], sx[p1]};
    py[j] = (v2f){sy[p0], sy[p1]};
    pz[j] = (v2f){sz[p0], sz[p1]};
    payx[j] = ((unsigned)(N_SUP - 1 - sorig[p0]) << 13) | (unsigned)p0;
    payy[j] = ((unsigned)(N_SUP - 1 - sorig[p1]) << 13) | (unsigned)p1;
    dm[j] = (v2f){1e10f, 1e10f};
  }
  float lox = px[0].x, hix = px[0].x;
  float loy = py[0].x, hiy = py[0].x;
  float loz = pz[0].x, hiz = pz[0].x;
#pragma unroll
  for (int j = 0; j < 8; ++j) {
    lox = fminf(lox, fminf(px[j].x, px[j].y));
    hix = fmaxf(hix, fmaxf(px[j].x, px[j].y));
    loy = fminf(loy, fminf(py[j].x, py[j].y));
    hiy = fmaxf(hiy, fmaxf(py[j].x, py[j].y));
    loz = fminf(loz, fminf(pz[j].x, pz[j].y));
    hiz = fmaxf(hiz, fmaxf(pz[j].x, pz[j].y));
  }
  float tval = 1e10f;                 // forces dirty at iter 1
  unsigned long long tkey = 0ull, wkey = 0ull;

  float lxp = bx[0], lyp = by[0], lzp = bz[0];
  float* q = qxyz + b * N_QPT * 3;
  if (t == 0) { q[0] = lxp; q[1] = lyp; q[2] = lzp; }
  const int wv = t >> 6;
  const bool is63 = (t & 63) == 63;

  for (int it = 1; it < N_QPT; ++it) {
    // dirty check (any fp rounding here is covered by the margin)
    float dxl = fmaxf(fmaxf(lox - lxp, lxp - hix), 0.0f);
    float dyl = fmaxf(fmaxf(loy - lyp, lyp - hiy), 0.0f);
    float dzl = fmaxf(fmaxf(loz - lzp, lzp - hiz), 0.0f);
    float db2 = dxl * dxl + dyl * dyl + dzl * dzl;
    bool dirty = db2 < tval * 1.0001f + 1e-12f;
    if (__ballot(dirty)) {
      if (dirty) {
        // x + (-lx) rounds identically to x - lx
        float nx = -lxp, ny = -lyp, nz = -lzp;
        v2f nx2 = (v2f){nx, nx}, ny2 = (v2f){ny, ny}, nz2 = (v2f){nz, nz};
        float lm = -1.0f;
#pragma unroll
        for (int j = 0; j < 8; ++j) {
#pragma clang fp contract(off)
          v2f dx = px[j] + nx2;
          v2f dy = py[j] + ny2;
          v2f dz = pz[j] + nz2;
          v2f s = dx * dx + dy * dy;
          s = s + dz * dz;
          v2f nd = __builtin_elementwise_min(dm[j], s);
          dm[j] = nd;
          lm = fmaxf(lm, fmaxf(nd.x, nd.y));
        }
        tval = lm;
        // payload of winner: max payload among equal values == smallest
        // original index (invorig is the high bits; fp max selects exactly)
        unsigned pay = 0u;
#pragma unroll
        for (int j = 0; j < 8; ++j) {
          if (dm[j].x == tval) pay = max(pay, payx[j]);
          if (dm[j].y == tval) pay = max(pay, payy[j]);
        }
        tkey = (((unsigned long long)__float_as_uint(tval)) << 32) | pay;
      }
      wkey = wavemax_u64(tkey);  // valid at lane 63
    }
    if (is63) skey[it & 1][wv] = wkey;
    __syncthreads();
    const ulonglong2* pk = (const ulonglong2*)&skey[it & 1][0];
    ulonglong2 A = pk[0], B = pk[1], C = pk[2], D = pk[3];
    unsigned long long k0 = (A.y > A.x) ? A.y : A.x;
    unsigned long long k1 = (B.y > B.x) ? B.y : B.x;
    unsigned long long k2 = (C.y > C.x) ? C.y : C.x;
    unsigned long long k3 = (D.y > D.x) ? D.y : D.x;
    k0 = (k1 > k0) ? k1 : k0;
    k2 = (k3 > k2) ? k3 : k2;
    k0 = (k2 > k0) ? k2 : k0;
    unsigned pos = (unsigned)k0 & 0x1FFFu;
    lxp = sx[pos]; lyp = sy[pos]; lzp = sz[pos];
    if (t == 0) { q[it * 3 + 0] = lxp; q[it * 3 + 1] = lyp; q[it * 3 + 2] = lzp; }
  }
}

// ---------------------------------------------------------------------------
// Ball query: one wave per query, both radii in one scan. First-K-by-index
// via ballot + prefix popcount; early exit when both lists are full; pad with
// the first in-ball index (always exists: the query point itself, d2==0).
// ---------------------------------------------------------------------------
__global__ __launch_bounds__(256) void ballquery_kernel(
    const float* __restrict__ qxyz, const float* __restrict__ xs,
    const float* __restrict__ ys, const float* __restrict__ zs,
    const float* __restrict__ bsq, int* __restrict__ idx0,
    int* __restrict__ idx1) {
  const int lane = threadIdx.x & 63;
  const int qg = (blockIdx.x * 256 + threadIdx.x) >> 6;  // 0..16383
  const int b = qg >> 11;
  const float qx = qxyz[qg * 3 + 0];
  const float qy = qxyz[qg * 3 + 1];
  const float qz = qxyz[qg * 3 + 2];
  const float A = sumsq3(qx, qy, qz);
  const float* sx = xs + b * N_SUP;
  const float* sy = ys + b * N_SUP;
  const float* sz = zs + b * N_SUP;
  const float* sq = bsq + b * N_SUP;
  int* o0 = idx0 + qg * 16;
  int* o1 = idx1 + qg * 32;
  int cnt0 = 0, cnt1 = 0, first0 = 0, first1 = 0;
  const unsigned long long ltmask = (1ull << lane) - 1ull;
  for (int base = 0; base < N_SUP; base += 64) {
    int n = base + lane;
    float d = dot3(qx, qy, qz, sx[n], sy[n], sz[n]);
    float d2 = d2_expand(A, sq[n], d);
    bool in1 = d2 <= 0.04f;  // == f32(0.2*0.2 in double)
    bool in0 = d2 <= 0.01f;  // == f32(0.1*0.1 in double)
    unsigned long long m1 = __ballot(in1);
    unsigned long long m0 = __ballot(in0);
    if (in1) {
      int pos = cnt1 + __popcll(m1 & ltmask);
      if (pos < 32) o1[pos] = n;
    }
    if (in0) {
      int pos = cnt0 + __popcll(m0 & ltmask);
      if (pos < 16) o0[pos] = n;
    }
    if (cnt1 == 0 && m1 != 0ull) first1 = base + __ffsll(m1) - 1;
    if (cnt0 == 0 && m0 != 0ull) first0 = base + __ffsll(m0) - 1;
    cnt1 += __popcll(m1);
    cnt0 += __popcll(m0);
    if (cnt0 >= 16 && cnt1 >= 32) break;
  }
  for (int p = cnt0 + lane; p < 16; p += 64) o0[p] = first0;
  for (int p = cnt1 + lane; p < 32; p += 64) o1[p] = first1;
}

// ---------------------------------------------------------------------------
// Grouped MLP. Block = 256 threads = 4 waves, 64 rows (= Q queries x K
// neighbors), lane == row. Activations in LDS with odd strides (bank-clean),
// weights are wave-uniform -> scalar loads feeding v_fmac: VALU-bound.
// ---------------------------------------------------------------------------
template <int CIN, int SIN, int D, int SOUT>
__device__ __forceinline__ void dense_layer(const float* __restrict__ hin,
                                            float* __restrict__ hout,
                                            const float* __restrict__ W,
                                            const float* __restrict__ Bv,
                                            int w, int lane) {
  constexpr int CH = D / 16;
#pragma unroll
  for (int pass = 0; pass * 4 < CH; ++pass) {
    const int chunk = pass * 4 + w;
    if (chunk < CH) {  // wave-uniform branch
      const int co = chunk * 16;
      float acc[16];
#pragma unroll
      for (int j = 0; j < 16; ++j) acc[j] = Bv[co + j];
      const float* hr = hin + lane * SIN;
      const float* wp = W + co;
#pragma unroll 4
      for (int c = 0; c < CIN; ++c) {
        float a = hr[c];
#pragma unroll
        for (int j = 0; j < 16; ++j) acc[j] = fmaf(a, wp[c * D + j], acc[j]);
      }
      float* ho = hout + lane * SOUT + co;
#pragma unroll
      for (int j = 0; j < 16; ++j) ho[j] = fmaxf(acc[j], 0.0f);
    }
  }
}

template <int K, int Q, int C2, int S2, int CHOFF>
__global__ __launch_bounds__(256, 4) void mlp_kernel(
    const int* __restrict__ idxl, const float* __restrict__ qxyz,
    const float* __restrict__ xs, const float* __restrict__ ys,
    const float* __restrict__ zs, const float* __restrict__ fT,
    const float* __restrict__ W1, const float* __restrict__ B1,
    const float* __restrict__ W2, const float* __restrict__ B2,
    const float* __restrict__ W3, const float* __restrict__ B3,
    float* __restrict__ outf) {
  constexpr int S0 = 67, S1 = 65;
  constexpr int H0 = 64 * S0, H1 = 64 * S1, H2 = 64 * S2;
  constexpr int SM = H1 + (H2 > H0 ? H2 : H0);
  __shared__ float smem[SM];
  float* h1 = smem;       // layer1 output
  float* h0 = smem + H1;  // gathered input; dead after layer1
  float* h2 = smem + H1;  // layer2 output overlays h0
  const int t = threadIdx.x;
  const int w = __builtin_amdgcn_readfirstlane(t >> 6);
  const int lane = t & 63;
  // ---- gather h0: [rel_x, rel_y, rel_z, feat0..63] per row ----
  for (int e = t; e < H0; e += 256) {
    int r = e / S0, c = e - r * S0;
    int qi = r / K, k = r - qi * K;
    int qg = blockIdx.x * Q + qi;
    int b = qg >> 11;
    int n = idxl[qg * K + k];
    float v;
    if (c < 3) {
      const float* sp = (c == 0) ? xs : (c == 1) ? ys : zs;
      v = sp[b * N_SUP + n] - qxyz[qg * 3 + c];
    } else {
      v = fT[(b * N_SUP + n) * 64 + (c - 3)];
    }
    h0[e] = v;
  }
  __syncthreads();
  dense_layer<67, S0, 64, S1>(h0, h1, W1, B1, w, lane);
  __syncthreads();
  dense_layer<64, S1, C2, S2>(h1, h2, W2, B2, w, lane);
  __syncthreads();
  // ---- layer3 (C2 -> 128) + relu + maxpool over K + channel-major write ----
#pragma unroll
  for (int pass = 0; pass < 2; ++pass) {
    const int co = (pass * 4 + w) * 16;
    float acc[16];
#pragma unroll
    for (int j = 0; j < 16; ++j) acc[j] = B3[co + j];
    const float* hr = h2 + lane * S2;
#pragma unroll 4
    for (int c = 0; c < C2; ++c) {
      float a = hr[c];
#pragma unroll
      for (int j = 0; j < 16; ++j) acc[j] = fmaf(a, W3[c * 128 + co + j], acc[j]);
    }
#pragma unroll
    for (int j = 0; j < 16; ++j) acc[j] = fmaxf(acc[j], 0.0f);
#pragma unroll
    for (int off = K / 2; off >= 1; off >>= 1) {
#pragma unroll
      for (int j = 0; j < 16; ++j)
        acc[j] = fmaxf(acc[j], __shfl_xor(acc[j], off));
    }
    if ((lane & (K - 1)) == 0) {
      int qg = blockIdx.x * Q + (lane / K);
      int b = qg >> 11, s = qg & 2047;
      float* dst = outf + ((b * 256 + CHOFF + co) * 2048 + s);
#pragma unroll
      for (int j = 0; j < 16; ++j) dst[j * 2048] = acc[j];
    }
  }
}

// ---------------------------------------------------------------------------
// ws layout (floats): xs[65536] ys[65536] zs[65536] bsq[65536]
// featsT[8*8192*64] then idx0 (8*2048*16 int), idx1 (8*2048*32 int) ~20 MB
// ---------------------------------------------------------------------------
extern "C" void kernel_launch(void* const* d_in, const int* in_sizes, int n_in,
                              void* d_out, int out_size, void* d_ws,
                              size_t ws_size, hipStream_t stream) {
  const float* xyz = (const float*)d_in[0];
  const float* feats = (const float*)d_in[1];
  const float* wt[12];
  for (int i = 0; i < 12; ++i) wt[i] = (const float*)d_in[2 + i];

  float* ws = (float*)d_ws;
  float* xs = ws;
  float* ys = ws + 65536;
  float* zs = ws + 131072;
  float* bsq = ws + 196608;
  float* fT = ws + 262144;                 // 4194304 floats
  int* idx0 = (int*)(ws + 4456448);        // 262144 ints
  int* idx1 = idx0 + 262144;               // 524288 ints

  float* qxyz = (float*)d_out;             // (8,2048,3)
  float* outf = qxyz + 8 * 2048 * 3;       // (8,256,2048)

  prep_xyz_kernel<<<dim3(256), dim3(256), 0, stream>>>(xyz, xs, ys, zs, bsq);
  transpose_feats_kernel<<<dim3(1024), dim3(256), 0, stream>>>(feats, fT);
  fps_kernel<<<dim3(8), dim3(512), 0, stream>>>(xs, ys, zs, qxyz);
  ballquery_kernel<<<dim3(4096), dim3(256), 0, stream>>>(qxyz, xs, ys, zs, bsq,
                                                         idx0, idx1);
  mlp_kernel<16, 4, 64, 65, 0><<<dim3(4096), dim3(256), 0, stream>>>(
      idx0, qxyz, xs, ys, zs, fT, wt[0], wt[1], wt[2], wt[3], wt[4], wt[5],
      outf);
  mlp_kernel<32, 2, 96, 97, 128><<<dim3(8192), dim3(256), 0, stream>>>(
      idx1, qxyz, xs, ys, zs, fT, wt[6], wt[7], wt[8], wt[9], wt[10], wt[11],
      outf);
}